// Round 9
// baseline (61.735 us; speedup 1.0000x reference)
//
#include <hip/hip_runtime.h>

#define MTOT 8192
#define NTOT 8192
#define DD   64
#define SPLIT (MTOT * DD)   // 524288 elems per hi/lo array

typedef __bf16 bf16x8 __attribute__((ext_vector_type(8)));
typedef float  f32x16 __attribute__((ext_vector_type(16)));
typedef unsigned short u16;
typedef unsigned short u16x4 __attribute__((ext_vector_type(4)));
typedef unsigned short u16x8 __attribute__((ext_vector_type(8)));

__device__ __forceinline__ u16 bf16_rne(float v) {
    unsigned int u = __float_as_uint(v);
    u = u + 0x7FFFu + ((u >> 16) & 1u);
    return (u16)(u >> 16);
}
__device__ __forceinline__ float bf16_to_f32(u16 h) {
    return __uint_as_float(((unsigned int)h) << 16);
}

#define MFMA(a, b, c) __builtin_amdgcn_mfma_f32_32x32x16_bf16((a), (b), (c), 0, 0, 0)

// ============ pre-pass: fp32 -> hi/lo bf16 in FRAGMENT-LINEAR order + norms ============
// elem(row,k) -> [(tt*4 + ks)*64 + lane]*8 + slot ; tt=row>>5, ks=k>>4,
// lane=(row&31)|(((k>>3)&1)<<5), slot=k&7.
__global__ __launch_bounds__(256)
void rbf_pre_kernel(const float* __restrict__ X, const float* __restrict__ Y,
                    u16* __restrict__ XhiF, u16* __restrict__ XloF,
                    u16* __restrict__ YhiF, u16* __restrict__ YloF,
                    float* __restrict__ xqs, float* __restrict__ yqs)
{
    const int gid = blockIdx.x * 256 + threadIdx.x;
    const int mat = gid >> 15;            // 0 = X, 1 = Y
    const int r4  = gid & 32767;
    const int row = r4 >> 2;
    const int q   = r4 & 3;               // == ks
    const float* src = mat ? Y : X;
    u16* hi  = mat ? YhiF : XhiF;
    u16* lo  = mat ? YloF : XloF;
    float* nrm = mat ? yqs : xqs;

    const long rbase = (long)row * DD + q * 16;
    float s = 0.f;
    u16x8 h0, h1, l0, l1;
    #pragma unroll
    for (int c = 0; c < 4; ++c) {
        const float4 v = *reinterpret_cast<const float4*>(src + rbase + c * 4);
        const float vv[4] = {v.x, v.y, v.z, v.w};
        #pragma unroll
        for (int e = 0; e < 4; ++e) {
            const int idx = c * 4 + e;
            const float x = vv[e];
            s = fmaf(x, x, s);
            const u16 hh = bf16_rne(x);
            const u16 ll = bf16_rne(x - bf16_to_f32(hh));
            if (idx < 8) { h0[idx] = hh; l0[idx] = ll; }
            else         { h1[idx - 8] = hh; l1[idx - 8] = ll; }
        }
    }
    s += __shfl_xor(s, 1);
    s += __shfl_xor(s, 2);
    if (q == 0) nrm[row] = s;

    const int tt = row >> 5, lr = row & 31;
    const long fbase = (long)(tt * 4 + q) * 512;
    *reinterpret_cast<u16x8*>(hi + fbase + lr * 8)        = h0;
    *reinterpret_cast<u16x8*>(hi + fbase + (32 + lr) * 8) = h1;
    *reinterpret_cast<u16x8*>(lo + fbase + lr * 8)        = l0;
    *reinterpret_cast<u16x8*>(lo + fbase + (32 + lr) * 8) = l1;
}

// ============ main: ROW-SLAB waves + contiguous-512B store groups ============
// 4096 blocks x 256 threads (4 waves), 64 KB LDS, 2 blocks/CU (R5 staging).
// Wave w owns rows [w*32, w*32+32) x all 128 cols: 4 quadrant accumulators.
// Epilogue walks jj fastest: 4 consecutive stores = contiguous 512B row span
// (x2 rows via lane halves) -> 4x larger DRAM-local write runs than R5.
__global__ __launch_bounds__(256, 2)
void rbf_rowslab_kernel(const u16* __restrict__ XhiF, const u16* __restrict__ XloF,
                        const u16* __restrict__ YhiF, const u16* __restrict__ YloF,
                        const float* __restrict__ xqs, const float* __restrict__ yqs,
                        const float* __restrict__ gamma_p,
                        float* __restrict__ out)
{
    __shared__ __align__(16) u16 S[4][8192];   // Xhi | Xlo | Yhi | Ylo panels

    const int t = threadIdx.x;
    const int w = t >> 6;
    const int l = t & 63;
    const int loff = l * 8;

    // bijective XCD swizzle: contiguous bm stripes per XCD; concurrent blocks
    // on one XCD have consecutive bn (same bm) -> adjacent 512B row chunks.
    const int bid = blockIdx.x;
    const int swz = ((bid & 7) << 9) | (bid >> 3);
    const int bm = swz >> 6;
    const int bn = swz & 63;
    const long row0 = (long)bm * 128;
    const long col0 = (long)bn * 128;

    // ---- stage: wave w copies its 16 KB panel (R5's proven plain-load path) ----
    {
        const u16* gsrc;
        if      (w == 0) gsrc = XhiF + (long)bm * 8192;
        else if (w == 1) gsrc = XloF + (long)bm * 8192;
        else if (w == 2) gsrc = YhiF + (long)bn * 8192;
        else             gsrc = YloF + (long)bn * 8192;
        u16* const ldst = &S[w][0];
        #pragma unroll
        for (int c = 0; c < 16; ++c) {
            const int off = c * 512 + loff;
            *reinterpret_cast<int4*>(ldst + off) = *reinterpret_cast<const int4*>(gsrc + off);
        }
    }

    // hoisted epilogue constants (overlap with staging latency)
    const float g  = gamma_p[0];
    const float g2 = 2.0f * g;
    const int l5x4 = (l >> 5) * 4;
    const int  ln  = l & 31;

    float xv[16];
    #pragma unroll
    for (int q4 = 0; q4 < 4; ++q4) {
        const float4 x4 = *reinterpret_cast<const float4*>(
            xqs + row0 + w * 32 + 8 * q4 + l5x4);
        xv[q4 * 4 + 0] = x4.x; xv[q4 * 4 + 1] = x4.y;
        xv[q4 * 4 + 2] = x4.z; xv[q4 * 4 + 3] = x4.w;
    }
    const float cy0 = -g * yqs[col0 +  0 + ln];
    const float cy1 = -g * yqs[col0 + 32 + ln];
    const float cy2 = -g * yqs[col0 + 64 + ln];
    const float cy3 = -g * yqs[col0 + 96 + ln];

    __syncthreads();   // staging visible

    // a-frags: this wave's single mt tile (rows w*32..w*32+31)
    bf16x8 aH[4], aL[4];
    #pragma unroll
    for (int ks = 0; ks < 4; ++ks) {
        aH[ks] = *reinterpret_cast<const bf16x8*>(&S[0][(w * 4 + ks) * 512 + loff]);
        aL[ks] = *reinterpret_cast<const bf16x8*>(&S[1][(w * 4 + ks) * 512 + loff]);
    }

    // 4 quadrant accumulators (cols jj*32..jj*32+31), split-bf16 hh+hl+lh
    f32x16 q0, q1, q2, q3;
    #pragma unroll
    for (int r = 0; r < 16; ++r) { q0[r] = 0.f; q1[r] = 0.f; q2[r] = 0.f; q3[r] = 0.f; }

#define QUAD(ACC, JJ)                                                                   \
    {                                                                                   \
        bf16x8 bh[4], bl[4];                                                            \
        _Pragma("unroll")                                                               \
        for (int ks = 0; ks < 4; ++ks) {                                                \
            bh[ks] = *reinterpret_cast<const bf16x8*>(&S[2][((JJ) * 4 + ks) * 512 + loff]); \
            bl[ks] = *reinterpret_cast<const bf16x8*>(&S[3][((JJ) * 4 + ks) * 512 + loff]); \
        }                                                                               \
        _Pragma("unroll")                                                               \
        for (int ks = 0; ks < 4; ++ks) {                                                \
            ACC = MFMA(aH[ks], bh[ks], ACC);                                            \
            ACC = MFMA(aH[ks], bl[ks], ACC);                                            \
            ACC = MFMA(aL[ks], bh[ks], ACC);                                            \
        }                                                                               \
    }

    QUAD(q0, 0)
    QUAD(q1, 1)
    QUAD(q2, 2)
    QUAD(q3, 3)
#undef QUAD

    // ---- epilogue: jj-fastest store order -> contiguous 512B row segments ----
    // C/D (verified, A=X first): m-row = (r&3)+8*(r>>2)+l5x4 [+w*32],
    //                            n-col = ln [+jj*32]
    float* const obase = out + (row0 + w * 32) * (long)NTOT + col0 + ln;
    #pragma unroll
    for (int r = 0; r < 16; ++r) {
        const int rr = (r & 3) + 8 * (r >> 2) + l5x4;
        float* const orow = obase + rr * (long)NTOT;
        const float nx = -g * xv[r];
        const float a0 = fminf(fmaf(g2, q0[r], nx + cy0), 0.f);
        const float a1 = fminf(fmaf(g2, q1[r], nx + cy1), 0.f);
        const float a2 = fminf(fmaf(g2, q2[r], nx + cy2), 0.f);
        const float a3 = fminf(fmaf(g2, q3[r], nx + cy3), 0.f);
        __builtin_nontemporal_store(__expf(a0), orow);
        __builtin_nontemporal_store(__expf(a1), orow + 32);
        __builtin_nontemporal_store(__expf(a2), orow + 64);
        __builtin_nontemporal_store(__expf(a3), orow + 96);
    }
}

// ============ fallback (R2-style, known-good) if ws too small ============
__global__ __launch_bounds__(256, 2)
void rbf_fallback_kernel(const float* __restrict__ X,
                         const float* __restrict__ Y,
                         const float* __restrict__ gamma_p,
                         float* __restrict__ out)
{
    __shared__ unsigned short XfH[4][4][64][8];
    __shared__ unsigned short XfL[4][4][64][8];
    __shared__ unsigned short YfH[4][4][64][8];
    __shared__ unsigned short YfL[4][4][64][8];
    __shared__ float xq[128];
    __shared__ float yq[128];

    const int t = threadIdx.x;
    const long row0 = (long)blockIdx.y * 128;
    const long col0 = (long)blockIdx.x * 128;

    {
        const int k0   = (t & 15) * 4;
        const int ks   = k0 >> 4;
        const int l32  = ((k0 >> 3) & 1) << 5;
        const int slot = k0 & 4;
        #pragma unroll
        for (int i = 0; i < 8; ++i) {
            const int row  = (t >> 4) + i * 16;
            const int mt   = row >> 5;
            const int lane = (row & 31) | l32;
            const float4 vx = *reinterpret_cast<const float4*>(X + (row0 + row) * DD + k0);
            const float4 vy = *reinterpret_cast<const float4*>(Y + (col0 + row) * DD + k0);
            float xv[4] = {vx.x, vx.y, vx.z, vx.w};
            float yv[4] = {vy.x, vy.y, vy.z, vy.w};
            u16x4 xh, xl, yh, yl;
            #pragma unroll
            for (int e = 0; e < 4; ++e) {
                const u16 hx = bf16_rne(xv[e]);
                xh[e] = hx; xl[e] = bf16_rne(xv[e] - bf16_to_f32(hx));
                const u16 hy = bf16_rne(yv[e]);
                yh[e] = hy; yl[e] = bf16_rne(yv[e] - bf16_to_f32(hy));
            }
            *reinterpret_cast<u16x4*>(&XfH[mt][ks][lane][slot]) = xh;
            *reinterpret_cast<u16x4*>(&XfL[mt][ks][lane][slot]) = xl;
            *reinterpret_cast<u16x4*>(&YfH[mt][ks][lane][slot]) = yh;
            *reinterpret_cast<u16x4*>(&YfL[mt][ks][lane][slot]) = yl;
        }
    }
    {
        const int r = t & 127;
        const float* p2 = (t < 128) ? (X + (row0 + r) * DD) : (Y + (col0 + r) * DD);
        float s0 = 0.f, s1 = 0.f, s2 = 0.f, s3 = 0.f;
        #pragma unroll
        for (int c = 0; c < 16; ++c) {
            const float4 v = reinterpret_cast<const float4*>(p2)[c];
            s0 = fmaf(v.x, v.x, s0); s1 = fmaf(v.y, v.y, s1);
            s2 = fmaf(v.z, v.z, s2); s3 = fmaf(v.w, v.w, s3);
        }
        const float s = (s0 + s1) + (s2 + s3);
        if (t < 128) xq[r] = s; else yq[r] = s;
    }
    __syncthreads();

    const int w = t >> 6;
    const int l = t & 63;
    const int mt0 = (w >> 1) * 2;
    const int nt0 = (w & 1) * 2;

    bf16x8 aH[2][4], aL[2][4];
    #pragma unroll
    for (int i = 0; i < 2; ++i)
        #pragma unroll
        for (int ks = 0; ks < 4; ++ks) {
            aH[i][ks] = *reinterpret_cast<const bf16x8*>(&XfH[mt0 + i][ks][l][0]);
            aL[i][ks] = *reinterpret_cast<const bf16x8*>(&XfL[mt0 + i][ks][l][0]);
        }

    f32x16 acc[2][2];
    #pragma unroll
    for (int i = 0; i < 2; ++i)
        #pragma unroll
        for (int j = 0; j < 2; ++j)
            #pragma unroll
            for (int r = 0; r < 16; ++r) acc[i][j][r] = 0.f;

    #pragma unroll
    for (int ks = 0; ks < 4; ++ks) {
        const bf16x8 b0h = *reinterpret_cast<const bf16x8*>(&YfH[nt0 + 0][ks][l][0]);
        const bf16x8 b1h = *reinterpret_cast<const bf16x8*>(&YfH[nt0 + 1][ks][l][0]);
        const bf16x8 b0l = *reinterpret_cast<const bf16x8*>(&YfL[nt0 + 0][ks][l][0]);
        const bf16x8 b1l = *reinterpret_cast<const bf16x8*>(&YfL[nt0 + 1][ks][l][0]);
        acc[0][0] = MFMA(aH[0][ks], b0h, acc[0][0]);
        acc[0][1] = MFMA(aH[0][ks], b1h, acc[0][1]);
        acc[1][0] = MFMA(aH[1][ks], b0h, acc[1][0]);
        acc[1][1] = MFMA(aH[1][ks], b1h, acc[1][1]);
        acc[0][0] = MFMA(aH[0][ks], b0l, acc[0][0]);
        acc[0][1] = MFMA(aH[0][ks], b1l, acc[0][1]);
        acc[1][0] = MFMA(aH[1][ks], b0l, acc[1][0]);
        acc[1][1] = MFMA(aH[1][ks], b1l, acc[1][1]);
        acc[0][0] = MFMA(aL[0][ks], b0h, acc[0][0]);
        acc[0][1] = MFMA(aL[0][ks], b1h, acc[0][1]);
        acc[1][0] = MFMA(aL[1][ks], b0h, acc[1][0]);
        acc[1][1] = MFMA(aL[1][ks], b1h, acc[1][1]);
    }

    const float g = gamma_p[0];
    const int l5x4 = (l >> 5) * 4;
    const int ln = l & 31;
    #pragma unroll
    for (int i = 0; i < 2; ++i) {
        const int mt = mt0 + i;
        float xv[16];
        #pragma unroll
        for (int r = 0; r < 16; ++r)
            xv[r] = xq[mt * 32 + (r & 3) + 8 * (r >> 2) + l5x4];
        #pragma unroll
        for (int j = 0; j < 2; ++j) {
            const int nt = nt0 + j;
            const float yv = yq[nt * 32 + ln];
            const long gr = row0 + mt * 32;
            const long gc = col0 + nt * 32 + ln;
            #pragma unroll
            for (int r = 0; r < 16; ++r) {
                float s = fmaf(-2.f, acc[i][j][r], xv[r] + yv);
                s = fmaxf(s, 0.f);
                const long rr = gr + (r & 3) + 8 * (r >> 2) + l5x4;
                out[rr * NTOT + gc] = __expf(-g * s);
            }
        }
    }
}

extern "C" void kernel_launch(void* const* d_in, const int* in_sizes, int n_in,
                              void* d_out, int out_size, void* d_ws, size_t ws_size,
                              hipStream_t stream) {
    (void)in_sizes; (void)n_in; (void)out_size;
    const float* X = (const float*)d_in[0];
    const float* Y = (const float*)d_in[1];
    const float* gamma_p = (const float*)d_in[2];
    float* out = (float*)d_out;

    const size_t need = 4 * (size_t)SPLIT * sizeof(u16) + (MTOT + NTOT) * sizeof(float);

    if (ws_size >= need) {
        u16* XhiF = (u16*)d_ws;
        u16* XloF = XhiF + SPLIT;
        u16* YhiF = XloF + SPLIT;
        u16* YloF = YhiF + SPLIT;
        float* xqs = (float*)(YloF + SPLIT);
        float* yqs = xqs + MTOT;
        rbf_pre_kernel<<<256, 256, 0, stream>>>(X, Y, XhiF, XloF, YhiF, YloF, xqs, yqs);
        rbf_rowslab_kernel<<<4096, 256, 0, stream>>>(XhiF, XloF, YhiF, YloF, xqs, yqs, gamma_p, out);
    } else {
        dim3 grid(NTOT / 128, MTOT / 128);
        rbf_fallback_kernel<<<grid, 256, 0, stream>>>(X, Y, gamma_p, out);
    }
}

// Round 10
// 56.672 us; speedup vs baseline: 1.0893x; 1.0893x over previous
//
#include <hip/hip_runtime.h>

#define MTOT 8192
#define NTOT 8192
#define DD   64
#define SPLIT (MTOT * DD)   // 524288 elems per hi/lo array

typedef __bf16 bf16x8 __attribute__((ext_vector_type(8)));
typedef float  f32x16 __attribute__((ext_vector_type(16)));
typedef unsigned short u16;
typedef unsigned short u16x4 __attribute__((ext_vector_type(4)));
typedef unsigned short u16x8 __attribute__((ext_vector_type(8)));

__device__ __forceinline__ u16 bf16_rne(float v) {
    unsigned int u = __float_as_uint(v);
    u = u + 0x7FFFu + ((u >> 16) & 1u);
    return (u16)(u >> 16);
}
__device__ __forceinline__ float bf16_to_f32(u16 h) {
    return __uint_as_float(((unsigned int)h) << 16);
}

#define MFMA(a, b, c) __builtin_amdgcn_mfma_f32_32x32x16_bf16((a), (b), (c), 0, 0, 0)

// ============ pre-pass: fp32 -> hi/lo bf16 in FRAGMENT-LINEAR order + norms ============
// elem(row,k) -> [(tt*4 + ks)*64 + lane]*8 + slot ; tt=row>>5, ks=k>>4,
// lane=(row&31)|(((k>>3)&1)<<5), slot=k&7.
__global__ __launch_bounds__(256)
void rbf_pre_kernel(const float* __restrict__ X, const float* __restrict__ Y,
                    u16* __restrict__ XhiF, u16* __restrict__ XloF,
                    u16* __restrict__ YhiF, u16* __restrict__ YloF,
                    float* __restrict__ xqs, float* __restrict__ yqs)
{
    const int gid = blockIdx.x * 256 + threadIdx.x;
    const int mat = gid >> 15;            // 0 = X, 1 = Y
    const int r4  = gid & 32767;
    const int row = r4 >> 2;
    const int q   = r4 & 3;               // == ks
    const float* src = mat ? Y : X;
    u16* hi  = mat ? YhiF : XhiF;
    u16* lo  = mat ? YloF : XloF;
    float* nrm = mat ? yqs : xqs;

    const long rbase = (long)row * DD + q * 16;
    float s = 0.f;
    u16x8 h0, h1, l0, l1;
    #pragma unroll
    for (int c = 0; c < 4; ++c) {
        const float4 v = *reinterpret_cast<const float4*>(src + rbase + c * 4);
        const float vv[4] = {v.x, v.y, v.z, v.w};
        #pragma unroll
        for (int e = 0; e < 4; ++e) {
            const int idx = c * 4 + e;
            const float x = vv[e];
            s = fmaf(x, x, s);
            const u16 hh = bf16_rne(x);
            const u16 ll = bf16_rne(x - bf16_to_f32(hh));
            if (idx < 8) { h0[idx] = hh; l0[idx] = ll; }
            else         { h1[idx - 8] = hh; l1[idx - 8] = ll; }
        }
    }
    s += __shfl_xor(s, 1);
    s += __shfl_xor(s, 2);
    if (q == 0) nrm[row] = s;

    const int tt = row >> 5, lr = row & 31;
    const long fbase = (long)(tt * 4 + q) * 512;
    *reinterpret_cast<u16x8*>(hi + fbase + lr * 8)        = h0;
    *reinterpret_cast<u16x8*>(hi + fbase + (32 + lr) * 8) = h1;
    *reinterpret_cast<u16x8*>(lo + fbase + lr * 8)        = l0;
    *reinterpret_cast<u16x8*>(lo + fbase + (32 + lr) * 8) = l1;
}

// ============ main: 64x128 tile, Y-only LDS (32 KB), A-frags from global ============
// 8192 blocks x 256 threads (4 waves), 4 blocks/CU (VGPR<=128, 32 KB LDS).
// Wave w: mt = w&1 (32-row half), nt pair = (w>>1)*2 + {0,1}. A-frags are
// wave-private -> loaded once from global (contiguous 1KB/lane-chunk, L2-hot).
// Doubled phase diversity (4 independent blocks/CU) keeps the store pipe fed.
__global__ __launch_bounds__(256, 4)
void rbf_hiocc_kernel(const u16* __restrict__ XhiF, const u16* __restrict__ XloF,
                      const u16* __restrict__ YhiF, const u16* __restrict__ YloF,
                      const float* __restrict__ xqs, const float* __restrict__ yqs,
                      const float* __restrict__ gamma_p,
                      float* __restrict__ out)
{
    __shared__ __align__(16) u16 S[2][8192];   // Yhi | Ylo panel (16 KB each)

    const int t = threadIdx.x;
    const int w = t >> 6;
    const int l = t & 63;
    const int loff = l * 8;

    // bijective XCD swizzle: 8192 blocks, 1024 contiguous per XCD ->
    // same-XCD blocks share bm stripes (X panels) + walk bn (Y L2-hot).
    const int bid = blockIdx.x;
    const int swz = ((bid & 7) << 10) | (bid >> 3);
    const int bm = swz >> 6;       // 0..127  (64-row stripes)
    const int bn = swz & 63;       // 0..63   (128-col panels)
    const long row0 = (long)bm * 64;
    const long col0 = (long)bn * 128;

    // ---- stage Y panel (hi+lo, 32 KB) cooperatively: 8 chunks per wave ----
    {
        const u16* const yh = YhiF + (long)bn * 8192;
        const u16* const yl = YloF + (long)bn * 8192;
        #pragma unroll
        for (int cc = 0; cc < 8; ++cc) {
            const int c = w * 8 + cc;        // 0..31 (16 hi + 16 lo)
            const u16* gsrc = (c < 16) ? (yh + c * 512) : (yl + (c - 16) * 512);
            u16* ldst = (c < 16) ? &S[0][c * 512] : &S[1][(c - 16) * 512];
            *reinterpret_cast<int4*>(ldst + loff) = *reinterpret_cast<const int4*>(gsrc + loff);
        }
    }

    const int mt  = w & 1;          // 32-row tile within the 64-row stripe
    const int nt0 = (w >> 1) * 2;   // first of two 32-col tiles

    // ---- A-frags straight from global (wave-private, contiguous, L2-hot) ----
    const long att = (long)(bm * 2 + mt);   // global 32-row tile index
    bf16x8 aH[4], aL[4];
    #pragma unroll
    for (int ks = 0; ks < 4; ++ks) {
        aH[ks] = *reinterpret_cast<const bf16x8*>(XhiF + (att * 4 + ks) * 512 + loff);
        aL[ks] = *reinterpret_cast<const bf16x8*>(XloF + (att * 4 + ks) * 512 + loff);
    }

    // hoisted epilogue constants (overlap with staging latency)
    const float g  = gamma_p[0];
    const float g2 = 2.0f * g;
    const int l5x4 = (l >> 5) * 4;
    const int  ln  = l & 31;

    float xv[16];
    #pragma unroll
    for (int q4 = 0; q4 < 4; ++q4) {
        const float4 x4 = *reinterpret_cast<const float4*>(
            xqs + row0 + mt * 32 + 8 * q4 + l5x4);
        xv[q4 * 4 + 0] = x4.x; xv[q4 * 4 + 1] = x4.y;
        xv[q4 * 4 + 2] = x4.z; xv[q4 * 4 + 3] = x4.w;
    }
    const float cy0 = -g * yqs[col0 + (nt0 + 0) * 32 + ln];
    const float cy1 = -g * yqs[col0 + (nt0 + 1) * 32 + ln];

    __syncthreads();   // Y staging visible

    // ---- MFMA: 2 quadrants (nt0, nt0+1), split-bf16 hh+hl+lh, K=64 ----
    f32x16 acc0, acc1;
    #pragma unroll
    for (int r = 0; r < 16; ++r) { acc0[r] = 0.f; acc1[r] = 0.f; }

    #pragma unroll
    for (int ks = 0; ks < 4; ++ks) {
        const bf16x8 b0h = *reinterpret_cast<const bf16x8*>(&S[0][((nt0 + 0) * 4 + ks) * 512 + loff]);
        const bf16x8 b1h = *reinterpret_cast<const bf16x8*>(&S[0][((nt0 + 1) * 4 + ks) * 512 + loff]);
        const bf16x8 b0l = *reinterpret_cast<const bf16x8*>(&S[1][((nt0 + 0) * 4 + ks) * 512 + loff]);
        const bf16x8 b1l = *reinterpret_cast<const bf16x8*>(&S[1][((nt0 + 1) * 4 + ks) * 512 + loff]);
        acc0 = MFMA(aH[ks], b0h, acc0);
        acc1 = MFMA(aH[ks], b1h, acc1);
        acc0 = MFMA(aH[ks], b0l, acc0);
        acc1 = MFMA(aH[ks], b1l, acc1);
        acc0 = MFMA(aL[ks], b0h, acc0);
        acc1 = MFMA(aL[ks], b1h, acc1);
    }

    // ---- epilogue: arg = -g*(xq+yq-2*dot) clamped <= 0; NT-store exp ----
    // C/D (verified): m-row = (r&3)+8*(r>>2)+l5x4 [+mt*32], n-col = ln [+nt*32]
    float* const obase = out + (row0 + mt * 32) * (long)NTOT + col0 + nt0 * 32 + ln;
    #pragma unroll
    for (int r = 0; r < 16; ++r) {
        const int rr = (r & 3) + 8 * (r >> 2) + l5x4;
        float* const orow = obase + rr * (long)NTOT;
        const float a0 = fminf(fmaf(g2, acc0[r], fmaf(-g, xv[r], cy0)), 0.f);
        const float a1 = fminf(fmaf(g2, acc1[r], fmaf(-g, xv[r], cy1)), 0.f);
        __builtin_nontemporal_store(__expf(a0), orow);
        __builtin_nontemporal_store(__expf(a1), orow + 32);
    }
}

// ============ fallback (R2-style, known-good) if ws too small ============
__global__ __launch_bounds__(256, 2)
void rbf_fallback_kernel(const float* __restrict__ X,
                         const float* __restrict__ Y,
                         const float* __restrict__ gamma_p,
                         float* __restrict__ out)
{
    __shared__ unsigned short XfH[4][4][64][8];
    __shared__ unsigned short XfL[4][4][64][8];
    __shared__ unsigned short YfH[4][4][64][8];
    __shared__ unsigned short YfL[4][4][64][8];
    __shared__ float xq[128];
    __shared__ float yq[128];

    const int t = threadIdx.x;
    const long row0 = (long)blockIdx.y * 128;
    const long col0 = (long)blockIdx.x * 128;

    {
        const int k0   = (t & 15) * 4;
        const int ks   = k0 >> 4;
        const int l32  = ((k0 >> 3) & 1) << 5;
        const int slot = k0 & 4;
        #pragma unroll
        for (int i = 0; i < 8; ++i) {
            const int row  = (t >> 4) + i * 16;
            const int mt   = row >> 5;
            const int lane = (row & 31) | l32;
            const float4 vx = *reinterpret_cast<const float4*>(X + (row0 + row) * DD + k0);
            const float4 vy = *reinterpret_cast<const float4*>(Y + (col0 + row) * DD + k0);
            float xv[4] = {vx.x, vx.y, vx.z, vx.w};
            float yv[4] = {vy.x, vy.y, vy.z, vy.w};
            u16x4 xh, xl, yh, yl;
            #pragma unroll
            for (int e = 0; e < 4; ++e) {
                const u16 hx = bf16_rne(xv[e]);
                xh[e] = hx; xl[e] = bf16_rne(xv[e] - bf16_to_f32(hx));
                const u16 hy = bf16_rne(yv[e]);
                yh[e] = hy; yl[e] = bf16_rne(yv[e] - bf16_to_f32(hy));
            }
            *reinterpret_cast<u16x4*>(&XfH[mt][ks][lane][slot]) = xh;
            *reinterpret_cast<u16x4*>(&XfL[mt][ks][lane][slot]) = xl;
            *reinterpret_cast<u16x4*>(&YfH[mt][ks][lane][slot]) = yh;
            *reinterpret_cast<u16x4*>(&YfL[mt][ks][lane][slot]) = yl;
        }
    }
    {
        const int r = t & 127;
        const float* p2 = (t < 128) ? (X + (row0 + r) * DD) : (Y + (col0 + r) * DD);
        float s0 = 0.f, s1 = 0.f, s2 = 0.f, s3 = 0.f;
        #pragma unroll
        for (int c = 0; c < 16; ++c) {
            const float4 v = reinterpret_cast<const float4*>(p2)[c];
            s0 = fmaf(v.x, v.x, s0); s1 = fmaf(v.y, v.y, s1);
            s2 = fmaf(v.z, v.z, s2); s3 = fmaf(v.w, v.w, s3);
        }
        const float s = (s0 + s1) + (s2 + s3);
        if (t < 128) xq[r] = s; else yq[r] = s;
    }
    __syncthreads();

    const int w = t >> 6;
    const int l = t & 63;
    const int mt0 = (w >> 1) * 2;
    const int nt0 = (w & 1) * 2;

    bf16x8 aH[2][4], aL[2][4];
    #pragma unroll
    for (int i = 0; i < 2; ++i)
        #pragma unroll
        for (int ks = 0; ks < 4; ++ks) {
            aH[i][ks] = *reinterpret_cast<const bf16x8*>(&XfH[mt0 + i][ks][l][0]);
            aL[i][ks] = *reinterpret_cast<const bf16x8*>(&XfL[mt0 + i][ks][l][0]);
        }

    f32x16 acc[2][2];
    #pragma unroll
    for (int i = 0; i < 2; ++i)
        #pragma unroll
        for (int j = 0; j < 2; ++j)
            #pragma unroll
            for (int r = 0; r < 16; ++r) acc[i][j][r] = 0.f;

    #pragma unroll
    for (int ks = 0; ks < 4; ++ks) {
        const bf16x8 b0h = *reinterpret_cast<const bf16x8*>(&YfH[nt0 + 0][ks][l][0]);
        const bf16x8 b1h = *reinterpret_cast<const bf16x8*>(&YfH[nt0 + 1][ks][l][0]);
        const bf16x8 b0l = *reinterpret_cast<const bf16x8*>(&YfL[nt0 + 0][ks][l][0]);
        const bf16x8 b1l = *reinterpret_cast<const bf16x8*>(&YfL[nt0 + 1][ks][l][0]);
        acc[0][0] = MFMA(aH[0][ks], b0h, acc[0][0]);
        acc[0][1] = MFMA(aH[0][ks], b1h, acc[0][1]);
        acc[1][0] = MFMA(aH[1][ks], b0h, acc[1][0]);
        acc[1][1] = MFMA(aH[1][ks], b1h, acc[1][1]);
        acc[0][0] = MFMA(aH[0][ks], b0l, acc[0][0]);
        acc[0][1] = MFMA(aH[0][ks], b1l, acc[0][1]);
        acc[1][0] = MFMA(aH[1][ks], b0l, acc[1][0]);
        acc[1][1] = MFMA(aH[1][ks], b1l, acc[1][1]);
        acc[0][0] = MFMA(aL[0][ks], b0h, acc[0][0]);
        acc[0][1] = MFMA(aL[0][ks], b1h, acc[0][1]);
        acc[1][0] = MFMA(aL[1][ks], b0h, acc[1][0]);
        acc[1][1] = MFMA(aL[1][ks], b1h, acc[1][1]);
    }

    const float g = gamma_p[0];
    const int l5x4 = (l >> 5) * 4;
    const int ln = l & 31;
    #pragma unroll
    for (int i = 0; i < 2; ++i) {
        const int mt = mt0 + i;
        float xv[16];
        #pragma unroll
        for (int r = 0; r < 16; ++r)
            xv[r] = xq[mt * 32 + (r & 3) + 8 * (r >> 2) + l5x4];
        #pragma unroll
        for (int j = 0; j < 2; ++j) {
            const int nt = nt0 + j;
            const float yv = yq[nt * 32 + ln];
            const long gr = row0 + mt * 32;
            const long gc = col0 + nt * 32 + ln;
            #pragma unroll
            for (int r = 0; r < 16; ++r) {
                float s = fmaf(-2.f, acc[i][j][r], xv[r] + yv);
                s = fmaxf(s, 0.f);
                const long rr = gr + (r & 3) + 8 * (r >> 2) + l5x4;
                out[rr * NTOT + gc] = __expf(-g * s);
            }
        }
    }
}

extern "C" void kernel_launch(void* const* d_in, const int* in_sizes, int n_in,
                              void* d_out, int out_size, void* d_ws, size_t ws_size,
                              hipStream_t stream) {
    (void)in_sizes; (void)n_in; (void)out_size;
    const float* X = (const float*)d_in[0];
    const float* Y = (const float*)d_in[1];
    const float* gamma_p = (const float*)d_in[2];
    float* out = (float*)d_out;

    const size_t need = 4 * (size_t)SPLIT * sizeof(u16) + (MTOT + NTOT) * sizeof(float);

    if (ws_size >= need) {
        u16* XhiF = (u16*)d_ws;
        u16* XloF = XhiF + SPLIT;
        u16* YhiF = XloF + SPLIT;
        u16* YloF = YhiF + SPLIT;
        float* xqs = (float*)(YloF + SPLIT);
        float* yqs = xqs + MTOT;
        rbf_pre_kernel<<<256, 256, 0, stream>>>(X, Y, XhiF, XloF, YhiF, YloF, xqs, yqs);
        rbf_hiocc_kernel<<<8192, 256, 0, stream>>>(XhiF, XloF, YhiF, YloF, xqs, yqs, gamma_p, out);
    } else {
        dim3 grid(NTOT / 128, MTOT / 128);
        rbf_fallback_kernel<<<grid, 256, 0, stream>>>(X, Y, gamma_p, out);
    }
}